// Round 9
// baseline (67.393 us; speedup 1.0000x reference)
//
#include <hip/hip_runtime.h>
#include <math.h>

#define NB 512
#define TT 26

typedef unsigned long long ull;
typedef unsigned int u32;

__device__ __forceinline__ float wave_sum(float v) {
#pragma unroll
  for (int o = 32; o > 0; o >>= 1) v += __shfl_xor(v, o, 64);
  return v;
}

template<int CTRL, int RM>
__device__ __forceinline__ float dpp_add(float x) {
  int y = __builtin_amdgcn_update_dpp(0, __float_as_int(x), CTRL, RM, 0xf, true);
  return x + __int_as_float(y);
}
// sum across 64 lanes via DPP; result valid in lane 63
__device__ __forceinline__ float wave_red63(float x) {
  x = dpp_add<0x111, 0xf>(x);
  x = dpp_add<0x112, 0xf>(x);
  x = dpp_add<0x114, 0xf>(x);
  x = dpp_add<0x118, 0xf>(x);
  x = dpp_add<0x142, 0xa>(x);
  x = dpp_add<0x143, 0xc>(x);
  return x;
}

// ---------------- k_pre: phase1 + phase2 per sample ----------------
__global__ __launch_bounds__(256) void k_pre(
    const float* __restrict__ masks, const float* __restrict__ bf,
    const float* __restrict__ seq, const int* __restrict__ length,
    const float* __restrict__ alpha_p,
    ull* __restrict__ amid, u32* __restrict__ alow, ull* __restrict__ fmsk,
    float* __restrict__ seg_part, float* __restrict__ cor_part,
    float* __restrict__ irr_part)
{
  int b = blockIdx.x, tid = threadIdx.x, lane = tid & 63, wv = tid >> 6;
  __shared__ float att[64 * TT];
  __shared__ float wsA[128];
  __shared__ float wpart[2], ps[4], pc[4];
  const float4* sb4 = (const float4*)(seq + (size_t)b * (64 * TT));
  float4* att4 = (float4*)att;
  for (int i = tid; i < 416; i += 256) att4[i] = sb4[i];
  __syncthreads();
  int n = length[b] - 1;
  float alpha = alpha_p[0];

  if (tid < 128) {
    int w = tid, k = w >> 1;
    int i0, i1; float c0, c1;
    if ((w & 1) == 0) {
      if (k == 0) { i0 = 0; i1 = 0; c0 = 1.f; c1 = 0.f; }
      else        { i0 = k - 1; i1 = k; c0 = 0.25f; c1 = 0.75f; }
    } else {
      if (k == 63) { i0 = 63; i1 = 63; c0 = 1.f; c1 = 0.f; }
      else         { i0 = k; i1 = k + 1; c0 = 0.75f; c1 = 0.25f; }
    }
    float S = 0.f, S2 = 0.f, A = 0.f;
    for (int t = 0; t < n; ++t) {
      float v = c0 * att[i0 * TT + t] + c1 * att[i1 * TT + t];
      float s = v * v;
      S += s; S2 += s * s;
      A += 1.f / (1.f + __expf(-70.f * (v - 0.1f)));
    }
    wsA[w] = A;
    float c = S * S - S2;
    c = wave_sum(c);
    if (lane == 0) wpart[wv] = c;
  }
  if (tid < 64) {
    int x = tid;
    for (int t = 0; t < TT; ++t) {
      bool pred = (t < n) && (att[x * TT + t] > alpha);
      ull m = __ballot(pred);
      if (x == 0) amid[(size_t)b * TT + t] = m;
    }
  } else if (tid < 128) {
    int x = tid - 64;
    for (int t = 0; t < TT; ++t) {
      bool pred = (x < 32) && (t < n) &&
                  (0.5f * (att[(2 * x) * TT + t] + att[(2 * x + 1) * TT + t]) > alpha);
      ull m = __ballot(pred);
      if (x == 0) alow[(size_t)b * TT + t] = (u32)m;
    }
  }
  __syncthreads();
  if (tid == 0) irr_part[b] = 0.5f * (wpart[0] + wpart[1]) / (float)n;

  const float* mb = masks + (size_t)b * 4096;
  const float* fb = bf + (size_t)b * 8192;
  float A = wsA[tid & 127];
  float cs = fminf(fmaxf(A, 0.f), 1.f);
  float ce_fore = log1pf(__expf(1.f - 2.f * cs));
  float seg_acc = 0.f, cor_acc = 0.f;
  for (int k = 0; k < 16; ++k) {
    int px = k * 256 + tid;
    float m = mb[px];
    float b0 = fb[px];
    float b1 = fb[4096 + px];
    float mx = fmaxf(b0, b1);
    float e0 = __expf(b0 - mx), e1 = __expf(b1 - mx);
    float inv = 1.f / (e0 + e1);
    float p0 = e0 * inv, p1 = e1 * inv;
    float pm = fmaxf(p0, p1);
    float lse = pm + log1pf(__expf(-fabsf(p1 - p0)));
    seg_acc += lse - ((m > 0.5f) ? p1 : p0);
    bool fore = b1 > b0;
    cor_acc += fore ? ce_fore : 0.313261687518222834f;
    ull fbm = __ballot(fore);
    if (lane == 0) fmsk[(size_t)b * 64 + k * 4 + wv] = fbm;
  }
  seg_acc = wave_red63(seg_acc);
  cor_acc = wave_red63(cor_acc);
  if (lane == 63) { ps[wv] = seg_acc; pc[wv] = cor_acc; }
  __syncthreads();
  if (tid == 0) {
    seg_part[b] = ps[0] + ps[1] + ps[2] + ps[3];
    cor_part[b] = pc[0] + pc[1] + pc[2] + pc[3];
  }
}

// ---------------- k_chars: LDS-staged streaming; mid blocks [0,512), low [512,640) ----------------
__global__ __launch_bounds__(1024) void k_chars(
    const float* __restrict__ cm, const float* __restrict__ cl,
    const ull* __restrict__ fmsk, const ull* __restrict__ amid,
    const u32* __restrict__ alow,
    float* __restrict__ out_mask, float* __restrict__ out_smid,
    float* __restrict__ out_slow,
    float* __restrict__ celm_part, float* __restrict__ cell_part,
    float* __restrict__ inter_mid, float* __restrict__ m1s_mid, float* __restrict__ m2s_mid,
    float* __restrict__ inter_low, float* __restrict__ m1s_low, float* __restrict__ m2s_low)
{
  int blk = blockIdx.x, tid = threadIdx.x, lane = tid & 63, wv = tid >> 6;
  __shared__ __align__(16) char smem[62816];

  if (blk < NB) {
    // ================= mid: one block per b =================
    float*  bufF   = (float*)smem;              // [14][1024]
    float4* buf4   = (float4*)smem;
    u32*    cbkA   = (u32*)(smem + 57344);      // [1024]
    ull*    s_bits = (ull*)(smem + 61440);      // [26]
    ull*    s_fmw  = (ull*)(smem + 61648);      // [64]
    u32*    s_cols = (u32*)(smem + 62160);      // [64]
    ull*    s_fmrow= (ull*)(smem + 62416);      // [16]
    float*  red_in = (float*)(smem + 62544);    // [26]
    float*  red_m1 = (float*)(smem + 62648);    // [26]
    float*  s_ce   = (float*)(smem + 62752);    // [16]
    int b = blk, px = tid, x = lane, y = wv;

    if (tid < TT) s_bits[tid] = amid[(size_t)b * TT + tid];
    else if (tid >= 32 && tid < 96) s_fmw[tid - 32] = fmsk[(size_t)b * 64 + (tid - 32)];
    const float4* cm4 = (const float4*)(cm + (size_t)b * 27648);
    for (int i = tid; i < 3584; i += 1024) buf4[i] = cm4[i];          // c = 0..13
    __syncthreads();                                                  // B1
    if (tid < 64) {
      u32 cb = 0;
#pragma unroll
      for (int t = 0; t < TT; ++t) cb |= (u32)((s_bits[t] >> tid) & 1ULL) << t;
      s_cols[tid] = cb;
    }
    float v[27];
#pragma unroll
    for (int c = 0; c < 14; ++c) v[c] = bufF[c * 1024 + px];
    __syncthreads();                                                  // B2
    for (int i = tid; i < 3328; i += 1024) buf4[i] = cm4[3584 + i];   // c = 14..26
    __syncthreads();                                                  // B3
#pragma unroll
    for (int c = 14; c < 27; ++c) v[c] = bufF[(c - 14) * 1024 + px];

    int word = x >> 5, p = (x & 31) * 2;
    ull r0 = s_fmw[4 * y + word], r1 = s_fmw[4 * y + 2 + word];
    int cnt = (int)((r0 >> p) & 1) + (int)((r0 >> (p + 1)) & 1)
            + (int)((r1 >> p) & 1) + (int)((r1 >> (p + 1)) & 1);
    bool fm = cnt >= 2;
    u32 cbk = s_cols[x];
    int lab = (fm && cbk) ? __ffs((int)cbk) : 0;
    if (!fm) cbk = 0;
    ull bmv = __ballot(fm);
    if (lane == 0) s_fmrow[wv] = bmv;
    cbkA[px] = cbk;

    float xl = 0.f, s0 = 0.f;
#pragma unroll
    for (int c = 0; c < 27; ++c) {
      float r = v[c];
      xl = (c == lab) ? r : xl;
      float e = __expf(r);
      v[c] = e;
      s0 += e;
    }
    float inv0 = 1.f / s0;
    float rce = wave_red63(__logf(s0) - xl);
    if (lane == 63) s_ce[wv] = rce;

#pragma unroll
    for (int t = 13; t < 26; ++t) bufF[(t - 13) * 1024 + px] = v[t + 1] * inv0;
    __syncthreads();                                                  // B4
    float4* smid4 = (float4*)(out_smid + (size_t)b * 26624);
    for (int i = tid; i < 3328; i += 1024) smid4[3328 + i] = buf4[i]; // rows 13..25
    if (wv < 13) {
      int t = 13 + wv;
      float isum = 0.f, msum = 0.f;
#pragma unroll
      for (int k = 0; k < 16; ++k) {
        int q = lane + 64 * k;
        float m1 = bufF[wv * 1024 + q];
        u32 cb = cbkA[q];
        msum += m1;
        isum += ((cb >> t) & 1) ? m1 : 0.f;
      }
      isum = wave_red63(isum); msum = wave_red63(msum);
      if (lane == 63) { red_in[t] = isum; red_m1[t] = msum; }
    }
    __syncthreads();                                                  // B5
#pragma unroll
    for (int t = 0; t < 13; ++t) bufF[t * 1024 + px] = v[t + 1] * inv0;
    __syncthreads();                                                  // B6
    for (int i = tid; i < 3328; i += 1024) smid4[i] = buf4[i];        // rows 0..12
    if (wv < 13) {
      int t = wv;
      float isum = 0.f, msum = 0.f;
#pragma unroll
      for (int k = 0; k < 16; ++k) {
        int q = lane + 64 * k;
        float m1 = bufF[wv * 1024 + q];
        u32 cb = cbkA[q];
        msum += m1;
        isum += ((cb >> t) & 1) ? m1 : 0.f;
      }
      isum = wave_red63(isum); msum = wave_red63(msum);
      if (lane == 63) { red_in[t] = isum; red_m1[t] = msum; }
    }
    __syncthreads();                                                  // B7
    if (tid < TT) {
      float m2v = 0.f;
#pragma unroll
      for (int r = 0; r < 16; ++r) m2v += (float)__popcll(s_fmrow[r] & s_bits[tid]);
      int o = b * TT + tid;
      m2s_mid[o] = m2v;
      inter_mid[o] = red_in[tid];
      m1s_mid[o] = red_m1[tid];
    }
    if (tid == TT) {
      float c16 = 0.f;
#pragma unroll
      for (int w = 0; w < 16; ++w) c16 += s_ce[w];
      celm_part[b] = c16;
    }
  } else {
    // ================= low: 4 samples per block, 2 pair-rounds =================
    int L = blk - NB;
    float*  bufF    = (float*)smem;             // [2][27][256]
    float4* buf4    = (float4*)smem;
    u32*    cbkL    = (u32*)(smem + 55296);     // [2][256]
    u32*    l_bits  = (u32*)(smem + 57344);     // [4][26]
    u32*    colsL   = (u32*)(smem + 57760);     // [4][32]
    ull*    fmw4    = (ull*)(smem + 58272);     // [4][64]
    u32*    fmrow32 = (u32*)(smem + 60320);     // [2][8]
    float*  ceL     = (float*)(smem + 60384);   // [8]

    if (tid < 104) l_bits[tid] = alow[(size_t)(L * 4) * TT + tid];
    else if (tid >= 128 && tid < 384) fmw4[tid - 128] = fmsk[(size_t)(L * 4) * 64 + (tid - 128)];
    __syncthreads();                                                  // LB0
    if (tid < 128) {
      int s = tid >> 5, xx = tid & 31;
      u32 cb = 0;
#pragma unroll
      for (int t = 0; t < TT; ++t) cb |= ((l_bits[s * TT + t] >> xx) & 1u) << t;
      colsL[tid] = cb;
    }
    const float4* cl4 = (const float4*)cl;
    float4* slow4 = (float4*)out_slow;
    float4* mask4 = (float4*)out_mask;

    for (int pr = 0; pr < 2; ++pr) {
      for (int i = tid; i < 3456; i += 1024) {
        int s = i / 1728, r = i - s * 1728;
        buf4[i] = cl4[(size_t)(L * 4 + 2 * pr + s) * 1728 + r];
      }
      __syncthreads();                                                // LBa
      if (tid < 512) {
        int s = tid >> 8, sl = 2 * pr + s;
        int px = tid & 255, y = px >> 5, xx = px & 31;
        int wb = 4 * xx + 1, word = wb >> 6, pp = wb & 63;
        ull r0 = fmw4[sl * 64 + (4 * y + 1) * 2 + word];
        ull r1 = fmw4[sl * 64 + (4 * y + 2) * 2 + word];
        int cnt = (int)((r0 >> pp) & 1) + (int)((r0 >> (pp + 1)) & 1)
                + (int)((r1 >> pp) & 1) + (int)((r1 >> (pp + 1)) & 1);
        bool fm = cnt >= 2;
        u32 cbk = colsL[sl * 32 + xx];
        int lab = (fm && cbk) ? __ffs((int)cbk) : 0;
        if (!fm) cbk = 0;
        ull bmv = __ballot(fm);
        if (lane == 0) {
          fmrow32[s * 8 + 2 * (wv & 3)] = (u32)bmv;
          fmrow32[s * 8 + 2 * (wv & 3) + 1] = (u32)(bmv >> 32);
        }
        float v[27];
#pragma unroll
        for (int c = 0; c < 27; ++c) v[c] = bufF[s * 6912 + c * 256 + px];
        float xl = 0.f, s0 = 0.f;
#pragma unroll
        for (int c = 0; c < 27; ++c) {
          float r = v[c];
          xl = (c == lab) ? r : xl;
          float e = __expf(r);
          v[c] = e;
          s0 += e;
        }
        float inv0 = 1.f / s0;
        float rce = wave_red63(__logf(s0) - xl);
        if (lane == 63) ceL[wv] = rce;
        bufF[s * 6912 + px] = fm ? 0.f : 1.f;
#pragma unroll
        for (int t = 0; t < TT; ++t) bufF[s * 6912 + (t + 1) * 256 + px] = v[t + 1] * inv0;
        cbkL[s * 256 + px] = cbk;
      }
      __syncthreads();                                                // LBb
      for (int i = tid; i < 3328; i += 1024) {
        int s = i / 1664, r = i - s * 1664;
        slow4[(size_t)(L * 4 + 2 * pr + s) * 1664 + r] = buf4[s * 1728 + 64 + r];
      }
      for (int i = tid; i < 3456; i += 1024) {
        int s = i / 1728, r = i - s * 1728;
        int c = r >> 6, off = r & 63;
        float4 o;
        if (c == 0) o = buf4[s * 1728 + off];
        else {
          int t = c - 1;
          o.x = ((cbkL[s * 256 + off * 4 + 0] >> t) & 1) ? 1.f : 0.f;
          o.y = ((cbkL[s * 256 + off * 4 + 1] >> t) & 1) ? 1.f : 0.f;
          o.z = ((cbkL[s * 256 + off * 4 + 2] >> t) & 1) ? 1.f : 0.f;
          o.w = ((cbkL[s * 256 + off * 4 + 3] >> t) & 1) ? 1.f : 0.f;
        }
        mask4[(size_t)(L * 4 + 2 * pr + s) * 1728 + r] = o;
      }
      if (tid < 512) {
        int s = wv >> 2;
        int bb2 = L * 4 + 2 * pr + s;
        for (int t = wv & 3; t < TT; t += 4) {
          float isum = 0.f, msum = 0.f;
#pragma unroll
          for (int k = 0; k < 4; ++k) {
            int q = lane + 64 * k;
            float m1 = bufF[s * 6912 + (t + 1) * 256 + q];
            u32 cb = cbkL[s * 256 + q];
            msum += m1;
            isum += ((cb >> t) & 1) ? m1 : 0.f;
          }
          isum = wave_red63(isum); msum = wave_red63(msum);
          if (lane == 63) { inter_low[bb2 * TT + t] = isum; m1s_low[bb2 * TT + t] = msum; }
        }
      }
      if (tid >= 512 && tid < 564) {
        int j = tid - 512;
        int s = j / TT, t = j - s * TT, sl = 2 * pr + s;
        float m2v = 0.f;
#pragma unroll
        for (int yy = 0; yy < 8; ++yy) m2v += (float)__popc(fmrow32[s * 8 + yy] & l_bits[sl * TT + t]);
        m2s_low[(L * 4 + sl) * TT + t] = m2v;
      }
      if (tid == 600) cell_part[L * 4 + 2 * pr] = ceL[0] + ceL[1] + ceL[2] + ceL[3];
      if (tid == 601) cell_part[L * 4 + 2 * pr + 1] = ceL[4] + ceL[5] + ceL[6] + ceL[7];
      __syncthreads();                                                // LBc
    }
  }
}

// ---------------- finalize scalars ----------------
__global__ __launch_bounds__(1024) void k_final(
    const float* __restrict__ seg_part, const float* __restrict__ cor_part,
    const float* __restrict__ irr_part, const float* __restrict__ celm_part,
    const float* __restrict__ cell_part,
    const float* __restrict__ inter_mid, const float* __restrict__ m1s_mid,
    const float* __restrict__ m2s_mid,
    const float* __restrict__ inter_low, const float* __restrict__ m1s_low,
    const float* __restrict__ m2s_low,
    const int* __restrict__ length, const int* __restrict__ iter_p,
    float* __restrict__ out)
{
  int tid = threadIdx.x;
  float dm = 0.f, dl = 0.f;
  for (int i = tid; i < NB * TT; i += 1024) {
    int b = i / TT, t = i - b * TT;
    int n = length[b] - 1;
    if (t < n) {
      float inv_n = 1.f / (float)n;
      dm += (1.f - (2.f * inter_mid[i] + 1.f) / (m1s_mid[i] + m2s_mid[i] + 1.f)) * inv_n;
      dl += (1.f - (2.f * inter_low[i] + 1.f) / (m1s_low[i] + m2s_low[i] + 1.f)) * inv_n;
    }
  }
  float ss = 0.f, sel = 0.f, ssel = 0.f;
  float irr = 0.f, cell = 0.f, celm = 0.f, cor = 0.f;
  for (int b = tid; b < NB; b += 1024) {
    float v = seg_part[b];
    ss += v;
    float val = v * (1.f / 4096.f);
    if (val < 1.f) { sel += 1.f; ssel += val; }
    irr += irr_part[b]; cell += cell_part[b]; celm += celm_part[b]; cor += cor_part[b];
  }
  dm = wave_sum(dm); dl = wave_sum(dl); ss = wave_sum(ss);
  sel = wave_sum(sel); ssel = wave_sum(ssel);
  irr = wave_sum(irr); celm = wave_sum(celm); cell = wave_sum(cell);
  cor = wave_sum(cor);
  __shared__ float red[9][16];
  int wv = tid >> 6;
  if ((tid & 63) == 0) {
    red[0][wv] = dm; red[1][wv] = dl; red[2][wv] = ss; red[3][wv] = sel;
    red[4][wv] = ssel; red[5][wv] = irr; red[6][wv] = celm; red[7][wv] = cell;
    red[8][wv] = cor;
  }
  __syncthreads();
  if (tid == 0) {
    float a[9];
#pragma unroll
    for (int j = 0; j < 9; ++j) {
      float s = 0.f;
      for (int i = 0; i < 16; ++i) s += red[j][i];
      a[j] = s;
    }
    float pred = (iter_p[0] > 20000) ? (a[4] / fmaxf(a[3], 1.f)) : (a[2] / 2097152.f);
    out[0] = pred;
    out[1] = a[8] / 2097152.f + a[5];
    out[2] = a[7] / 131072.f + a[1] / 512.f;   // loss_low
    out[3] = a[6] / 524288.f + a[0] / 512.f;   // loss_middle
  }
}

extern "C" void kernel_launch(void* const* d_in, const int* in_sizes, int n_in,
                              void* d_out, int out_size, void* d_ws, size_t ws_size,
                              hipStream_t stream) {
  (void)in_sizes; (void)n_in; (void)out_size; (void)ws_size;
  const float* masks  = (const float*)d_in[0];
  const float* bf     = (const float*)d_in[1];
  const float* seq    = (const float*)d_in[2];
  const float* cmid   = (const float*)d_in[3];
  const float* clow   = (const float*)d_in[4];
  const int*   length = (const int*)d_in[5];
  const int*   iter   = (const int*)d_in[6];
  const float* alpha  = (const float*)d_in[7];
  float* out = (float*)d_out;

  char* ws = (char*)d_ws;
  // all scratch fully rewritten every launch -> no memset
  float* seg_part  = (float*)(ws + 0);        // 512 f32
  float* cor_part  = (float*)(ws + 2048);
  float* irr_part  = (float*)(ws + 4096);
  float* celm_part = (float*)(ws + 6144);
  float* cell_part = (float*)(ws + 8192);
  float* inter_mid = (float*)(ws + 10240);    // 13312 f32 each
  float* m1s_mid   = (float*)(ws + 63488);
  float* m2s_mid   = (float*)(ws + 116736);
  float* inter_low = (float*)(ws + 169984);
  float* m1s_low   = (float*)(ws + 223232);
  float* m2s_low   = (float*)(ws + 276480);
  ull* amid = (ull*)(ws + 329728);            // 512*26 u64
  u32* alow = (u32*)(ws + 436224);            // 512*26 u32
  ull* fmsk = (ull*)(ws + 489472);            // 512*64 u64, ends 751616

  float* out_mask = out + 4;
  float* out_smid = out + 4 + 3538944;
  float* out_slow = out + 4 + 3538944 + 13631488;

  k_pre<<<NB, 256, 0, stream>>>(masks, bf, seq, length, alpha,
                                amid, alow, fmsk, seg_part, cor_part, irr_part);
  k_chars<<<NB + NB / 4, 1024, 0, stream>>>(cmid, clow, fmsk, amid, alow,
                                            out_mask, out_smid, out_slow,
                                            celm_part, cell_part,
                                            inter_mid, m1s_mid, m2s_mid,
                                            inter_low, m1s_low, m2s_low);
  k_final<<<1, 1024, 0, stream>>>(seg_part, cor_part, irr_part, celm_part, cell_part,
                                  inter_mid, m1s_mid, m2s_mid,
                                  inter_low, m1s_low, m2s_low, length, iter, out);
}